// Round 15
// baseline (130.280 us; speedup 1.0000x reference)
//
#include <hip/hip_runtime.h>
#include <hip/hip_bf16.h>
#include <cstdint>
#include <cstddef>

#define VOCAB 32000
#define HIDDEN 2048
#define NLAYERS 6
#define BATCH 512

#define BM 64
#define BN 64
#define BK 64
#define SPLITK 4
#define KC (HIDDEN / SPLITK)  // 512 K per block
#define NT (KC / BK)          // 8 K-tiles
#define GEMM_BLOCKS 1024
#define TRANS_BLOCKS 1024
#define CVT_BLOCKS 1024

typedef __attribute__((ext_vector_type(8))) short bf16x8;
typedef __attribute__((ext_vector_type(4))) float f32x4;

__device__ __forceinline__ unsigned short f2bf(float f) {
  unsigned u = __builtin_bit_cast(unsigned, f);
  u += 0x7fffu + ((u >> 16) & 1u);  // RNE
  return (unsigned short)(u >> 16);
}

__device__ __forceinline__ float bf2f(unsigned short h) {
  return __builtin_bit_cast(float, (unsigned)h << 16);
}

__device__ __forceinline__ float tanh_fast(float x) {
  x = fminf(15.f, fmaxf(-15.f, x));
  float e = __expf(2.f * x);
  return (e - 1.f) / (e + 1.f);
}

__device__ __forceinline__ void gload_lds16(const void* g, void* l) {
  __builtin_amdgcn_global_load_lds(
      (const __attribute__((address_space(1))) void*)g,
      (__attribute__((address_space(3))) void*)l, 16, 0, 0);
}

// ---- shared transpose tile body: hh fp32 [K][N] 64x64 tile -> bt bf16 [N][K] ----
__device__ __forceinline__ void transpose_tile(const float* __restrict__ src_layer,
                                               unsigned short* __restrict__ dst_layer,
                                               int n0, int k0, int t,
                                               unsigned short (*tile)[72]) {
  const float* src = src_layer + (size_t)k0 * HIDDEN + n0;
  const int cr = t >> 4;        // 0..15
  const int cc = (t & 15) * 4;  // 0..60
#pragma unroll
  for (int p = 0; p < 4; ++p) {
    const int r = p * 16 + cr;
    float4 v = *(const float4*)(src + (size_t)r * HIDDEN + cc);
    tile[r][cc + 0] = f2bf(v.x);
    tile[r][cc + 1] = f2bf(v.y);
    tile[r][cc + 2] = f2bf(v.z);
    tile[r][cc + 3] = f2bf(v.w);
  }
  __syncthreads();
  const int nl = t >> 2;        // output row (n), 0..63
  const int kk = (t & 3) * 16;  // k chunk
  unsigned short tmp[16] __attribute__((aligned(16)));
#pragma unroll
  for (int j = 0; j < 16; ++j) tmp[j] = tile[kk + j][nl];
  unsigned short* dst = dst_layer + (size_t)(n0 + nl) * HIDDEN + k0 + kk;
  *(uint4*)(dst) = *(const uint4*)(tmp);
  *(uint4*)(dst + 8) = *(const uint4*)(tmp + 8);
}

// ---- prep0: transpose layer 0 + cvt initial state ----
__global__ __launch_bounds__(256) void k_prep0(const float* __restrict__ hh0,
                                               unsigned short* __restrict__ bt0,
                                               const float* __restrict__ state,
                                               unsigned short* __restrict__ stb) {
  __shared__ unsigned short tile[64][72];
  const int wg = blockIdx.x;
  const int t = threadIdx.x;
  if (wg < TRANS_BLOCKS) {
    transpose_tile(hh0, bt0, (wg & 31) * 64, (wg >> 5) * 64, t, tile);
    return;
  }
  const int i = ((wg - TRANS_BLOCKS) * 256 + t) * 4;
  float4 v = *(const float4*)(state + i);
  union { unsigned short h[4]; uint2 u; } o;
  o.h[0] = f2bf(v.x); o.h[1] = f2bf(v.y); o.h[2] = f2bf(v.z); o.h[3] = f2bf(v.w);
  *(uint2*)(stb + i) = o.u;
}

// ---- combined: GEMM and transpose blocks interleaved in groups of 8 so both
// kinds co-reside on every CU (transpose HBM traffic hides under GEMM stalls;
// group-of-8 keeps id&7 == wg&7 so the XCD-grouped B-panel map stays physical).
__global__ __launch_bounds__(256, 4) void k_gemm_trans(
    const unsigned short* __restrict__ A, const unsigned short* __restrict__ Bt,
    unsigned short* __restrict__ part,
    const float* __restrict__ hhNext, unsigned short* __restrict__ btNext) {
  __shared__ __attribute__((aligned(16))) unsigned char smem[32768];
  const int t = threadIdx.x;
  const int wg = blockIdx.x;

  int id;
  bool isTrans;
  if (gridDim.x == GEMM_BLOCKS) {  // last layer: no transpose blocks
    isTrans = false;
    id = wg;
  } else {
    isTrans = (wg >> 3) & 1;
    id = ((wg >> 4) << 3) | (wg & 7);
  }

  if (isTrans) {
    transpose_tile(hhNext, btNext, (id & 31) * 64, (id >> 5) * 64, t,
                   (unsigned short(*)[72])smem);
    return;
  }

  unsigned short (*As)[BM][BK] = (unsigned short(*)[BM][BK])smem;            // [2]
  unsigned short (*Bs)[BN][BK] = (unsigned short(*)[BN][BK])(smem + 16384);  // [2]

  const int xcd = id & 7;
  const int idx = id >> 3;
  const int n0 = (xcd * 4 + (idx & 3)) * BN;
  const int m0 = ((idx >> 2) & 7) * BM;
  const int kz = idx >> 5;
  const int kbase = kz * KC;
  const int lane = t & 63;
  const int wid = t >> 6;
  const int wm = (wid >> 1) * 32;
  const int wn = (wid & 1) * 32;

  f32x4 zero = {0.f, 0.f, 0.f, 0.f};
  f32x4 acc[2][2];
  acc[0][0] = zero; acc[0][1] = zero; acc[1][0] = zero; acc[1][1] = zero;

  // T2 both-sides swizzle: pre-swizzled global source + linear LDS dest +
  // swizzled ds_read.
  const int r0 = t >> 3;
  const int sc = ((t & 7) ^ (r0 & 7)) * 8;
  const unsigned short* gA = A + (size_t)(m0 + r0) * HIDDEN + kbase + sc;
  const unsigned short* gB = Bt + (size_t)(n0 + r0) * HIDDEN + kbase + sc;
  char* lA = (char*)smem + wid * 1024;
  char* lB = (char*)smem + 16384 + wid * 1024;

#define STAGE(buf, kt)                                          \
  do {                                                          \
    const int ko = (kt)*BK;                                     \
    gload_lds16(gA + ko, lA + (buf)*8192);                      \
    gload_lds16(gA + 32 * HIDDEN + ko, lA + (buf)*8192 + 4096); \
    gload_lds16(gB + ko, lB + (buf)*8192);                      \
    gload_lds16(gB + 32 * HIDDEN + ko, lB + (buf)*8192 + 4096); \
  } while (0)

  const int row_a0 = wm + (lane & 15);
  const int row_a1 = row_a0 + 16;
  const int row_b0 = wn + (lane & 15);
  const int row_b1 = row_b0 + 16;
  const int q = lane >> 4;  // 0..3

#define COMPUTE(buf)                                                                    \
  do {                                                                                  \
    _Pragma("unroll") for (int ks = 0; ks < 2; ++ks) {                                  \
      const int cnk = ks * 4 + q;                                                       \
      bf16x8 a0 = *(const bf16x8*)&As[buf][row_a0][(cnk ^ (row_a0 & 7)) * 8];           \
      bf16x8 a1 = *(const bf16x8*)&As[buf][row_a1][(cnk ^ (row_a1 & 7)) * 8];           \
      bf16x8 b0 = *(const bf16x8*)&Bs[buf][row_b0][(cnk ^ (row_b0 & 7)) * 8];           \
      bf16x8 b1 = *(const bf16x8*)&Bs[buf][row_b1][(cnk ^ (row_b1 & 7)) * 8];           \
      acc[0][0] = __builtin_amdgcn_mfma_f32_16x16x32_bf16(a0, b0, acc[0][0], 0, 0, 0);  \
      acc[0][1] = __builtin_amdgcn_mfma_f32_16x16x32_bf16(a0, b1, acc[0][1], 0, 0, 0);  \
      acc[1][0] = __builtin_amdgcn_mfma_f32_16x16x32_bf16(a1, b0, acc[1][0], 0, 0, 0);  \
      acc[1][1] = __builtin_amdgcn_mfma_f32_16x16x32_bf16(a1, b1, acc[1][1], 0, 0, 0);  \
    }                                                                                   \
  } while (0)

  // Counted-vmcnt pipeline, 2 buffers, depth-1 in flight (r12-validated).
  STAGE(0, 0);
  for (int kt = 0; kt < NT; ++kt) {
    const int buf = kt & 1;
    if (kt + 1 < NT) {
      STAGE(buf ^ 1, kt + 1);
      asm volatile("s_waitcnt vmcnt(4)" ::: "memory");
    } else {
      asm volatile("s_waitcnt vmcnt(0)" ::: "memory");
    }
    __builtin_amdgcn_s_barrier();  // stage kt visible to all waves
    COMPUTE(buf);
    asm volatile("s_waitcnt lgkmcnt(0)" ::: "memory");
    __builtin_amdgcn_s_barrier();  // all waves done reading buf -> safe to restage
  }

  unsigned short* p = part + (size_t)kz * ((size_t)BATCH * HIDDEN);
  const int rb = m0 + wm + (q << 2);
  const int cb = n0 + wn + (lane & 15);
#pragma unroll
  for (int fm = 0; fm < 2; ++fm)
#pragma unroll
    for (int fn = 0; fn < 2; ++fn)
#pragma unroll
      for (int j = 0; j < 4; ++j)
        p[(size_t)(rb + fm * 16 + j) * HIDDEN + cb + fn * 16] = f2bf(acc[fm][fn][j]);
}

// ---- per-layer epilogue: sum bf16 partials, gate, tanh; state bf16 in-place ----
__global__ __launch_bounds__(256) void k_reduce(const unsigned short* __restrict__ part,
                                                const float* __restrict__ prevf,
                                                unsigned short* __restrict__ stb,
                                                const float* __restrict__ ihl,
                                                const int* __restrict__ token,
                                                float* __restrict__ outf) {
  const int idx = (blockIdx.x * 256 + threadIdx.x) * 4;
  const int m = idx >> 11;
  const int n = idx & 2047;
  const size_t MN = (size_t)BATCH * HIDDEN;
  float s[4] = {0.f, 0.f, 0.f, 0.f};
#pragma unroll
  for (int kz = 0; kz < SPLITK; ++kz) {
    union { uint2 u; unsigned short h[4]; } v;
    v.u = *(const uint2*)(part + kz * MN + idx);
#pragma unroll
    for (int j = 0; j < 4; ++j) s[j] += bf2f(v.h[j]);
  }
  float pv[4];
  if (prevf) {
    float4 p4 = *(const float4*)(prevf + idx);
    pv[0] = p4.x; pv[1] = p4.y; pv[2] = p4.z; pv[3] = p4.w;
  } else {
    union { uint2 u; unsigned short h[4]; } p2;
    p2.u = *(const uint2*)(stb + idx);
#pragma unroll
    for (int j = 0; j < 4; ++j) pv[j] = bf2f(p2.h[j]);
  }
  const int tok = token[m];
  float4 g = *(const float4*)(ihl + (size_t)tok * HIDDEN + n);
  float r[4];
  r[0] = tanh_fast(pv[0] + s[0] * g.x);
  r[1] = tanh_fast(pv[1] + s[1] * g.y);
  r[2] = tanh_fast(pv[2] + s[2] * g.z);
  r[3] = tanh_fast(pv[3] + s[3] * g.w);
  if (outf) {
    float4 o4 = {r[0], r[1], r[2], r[3]};
    *(float4*)(outf + idx) = o4;
  } else {
    union { unsigned short h[4]; uint2 u; } o;
    o.h[0] = f2bf(r[0]); o.h[1] = f2bf(r[1]); o.h[2] = f2bf(r[2]); o.h[3] = f2bf(r[3]);
    *(uint2*)(stb + idx) = o.u;
  }
}

extern "C" void kernel_launch(void* const* d_in, const int* in_sizes, int n_in,
                              void* d_out, int out_size, void* d_ws, size_t ws_size,
                              hipStream_t stream) {
  const float* state = (const float*)d_in[0];
  const int* token = (const int*)d_in[1];
  const float* ih = (const float*)d_in[2];
  const float* hh = (const float*)d_in[3];
  float* out = (float*)d_out;

  // ws layout (16B-aligned):
  //   Bt   : 6*2048*2048 bf16 = 50331648 B
  //   stb  : 512*2048 bf16    =  2097152 B
  //   part : 4*512*2048 bf16  =  8388608 B
  char* ws = (char*)d_ws;
  unsigned short* bt = (unsigned short*)ws;
  size_t off = (size_t)NLAYERS * HIDDEN * HIDDEN * 2;
  unsigned short* stb = (unsigned short*)(ws + off);
  off += (size_t)BATCH * HIDDEN * 2;
  unsigned short* part = (unsigned short*)(ws + off);

  k_prep0<<<dim3(TRANS_BLOCKS + CVT_BLOCKS), 256, 0, stream>>>(hh, bt, state, stb);

  for (int l = 0; l < NLAYERS; ++l) {
    const bool last = (l == NLAYERS - 1);
    const int nblocks = GEMM_BLOCKS + (last ? 0 : TRANS_BLOCKS);
    k_gemm_trans<<<dim3(nblocks), 256, 0, stream>>>(
        stb, bt + (size_t)l * HIDDEN * HIDDEN, part,
        last ? nullptr : hh + (size_t)(l + 1) * HIDDEN * HIDDEN,
        last ? nullptr : bt + (size_t)(l + 1) * HIDDEN * HIDDEN);
    k_reduce<<<dim3((BATCH * HIDDEN) / 1024), 256, 0, stream>>>(
        part, l == 0 ? state : nullptr, stb,
        ih + (size_t)l * VOCAB * HIDDEN, token, last ? out : nullptr);
  }
}

// Round 16
// 110.186 us; speedup vs baseline: 1.1824x; 1.1824x over previous
//
#include <hip/hip_runtime.h>
#include <hip/hip_bf16.h>
#include <cstdint>
#include <cstddef>

#define VOCAB 32000
#define HIDDEN 2048
#define NLAYERS 6
#define BATCH 512

#define BM 64
#define BN 64
#define BK 64
#define SPLITK 4
#define KC (HIDDEN / SPLITK)  // 512 K per block
#define NT (KC / BK)          // 8 K-tiles
#define GEMM_BLOCKS 1024
#define TRANS_BLOCKS 1024
#define CVT_BLOCKS 1024

typedef __attribute__((ext_vector_type(8))) short bf16x8;
typedef __attribute__((ext_vector_type(4))) float f32x4;

__device__ __forceinline__ unsigned short f2bf(float f) {
  unsigned u = __builtin_bit_cast(unsigned, f);
  u += 0x7fffu + ((u >> 16) & 1u);  // RNE
  return (unsigned short)(u >> 16);
}

__device__ __forceinline__ float bf2f(unsigned short h) {
  return __builtin_bit_cast(float, (unsigned)h << 16);
}

__device__ __forceinline__ float tanh_fast(float x) {
  x = fminf(15.f, fmaxf(-15.f, x));
  float e = __expf(2.f * x);
  return (e - 1.f) / (e + 1.f);
}

__device__ __forceinline__ void gload_lds16(const void* g, void* l) {
  __builtin_amdgcn_global_load_lds(
      (const __attribute__((address_space(1))) void*)g,
      (__attribute__((address_space(3))) void*)l, 16, 0, 0);
}

// ---- shared transpose tile body: hh fp32 [K][N] 64x64 tile -> bt bf16 [N][K] ----
__device__ __forceinline__ void transpose_tile(const float* __restrict__ src_layer,
                                               unsigned short* __restrict__ dst_layer,
                                               int n0, int k0, int t,
                                               unsigned short (*tile)[72]) {
  const float* src = src_layer + (size_t)k0 * HIDDEN + n0;
  const int cr = t >> 4;        // 0..15
  const int cc = (t & 15) * 4;  // 0..60
#pragma unroll
  for (int p = 0; p < 4; ++p) {
    const int r = p * 16 + cr;
    float4 v = *(const float4*)(src + (size_t)r * HIDDEN + cc);
    tile[r][cc + 0] = f2bf(v.x);
    tile[r][cc + 1] = f2bf(v.y);
    tile[r][cc + 2] = f2bf(v.z);
    tile[r][cc + 3] = f2bf(v.w);
  }
  __syncthreads();
  const int nl = t >> 2;        // output row (n), 0..63
  const int kk = (t & 3) * 16;  // k chunk
  unsigned short tmp[16] __attribute__((aligned(16)));
#pragma unroll
  for (int j = 0; j < 16; ++j) tmp[j] = tile[kk + j][nl];
  unsigned short* dst = dst_layer + (size_t)(n0 + nl) * HIDDEN + k0 + kk;
  *(uint4*)(dst) = *(const uint4*)(tmp);
  *(uint4*)(dst + 8) = *(const uint4*)(tmp + 8);
}

// ---- prep0: transpose layer 0 + cvt initial state ----
__global__ __launch_bounds__(256) void k_prep0(const float* __restrict__ hh0,
                                               unsigned short* __restrict__ bt0,
                                               const float* __restrict__ state,
                                               unsigned short* __restrict__ stb) {
  __shared__ unsigned short tile[64][72];
  const int wg = blockIdx.x;
  const int t = threadIdx.x;
  if (wg < TRANS_BLOCKS) {
    transpose_tile(hh0, bt0, (wg & 31) * 64, (wg >> 5) * 64, t, tile);
    return;
  }
  const int i = ((wg - TRANS_BLOCKS) * 256 + t) * 4;
  float4 v = *(const float4*)(state + i);
  union { unsigned short h[4]; uint2 u; } o;
  o.h[0] = f2bf(v.x); o.h[1] = f2bf(v.y); o.h[2] = f2bf(v.z); o.h[3] = f2bf(v.w);
  *(uint2*)(stb + i) = o.u;
}

// ---- combined: blocks 0..1023 = layer-l GEMM; 1024..2047 = transpose layer l+1.
// __launch_bounds__(256,5): LDS 32KB -> 5 blocks/CU (160KB), so the first
// dispatch round holds all 1024 GEMM blocks PLUS 256 transpose blocks --
// transpose HBM traffic overlaps the GEMM without displacing GEMM blocks
// (r15 showed displacement costs ~20us; r14's 4/CU serialized the transpose).
__global__ __launch_bounds__(256, 5) void k_gemm_trans(
    const unsigned short* __restrict__ A, const unsigned short* __restrict__ Bt,
    unsigned short* __restrict__ part,
    const float* __restrict__ hhNext, unsigned short* __restrict__ btNext) {
  __shared__ __attribute__((aligned(16))) unsigned char smem[32768];
  const int t = threadIdx.x;
  const int wg = blockIdx.x;

  if (wg >= GEMM_BLOCKS) {
    const int tn = wg - GEMM_BLOCKS;
    transpose_tile(hhNext, btNext, (tn & 31) * 64, (tn >> 5) * 64, t,
                   (unsigned short(*)[72])smem);
    return;
  }

  unsigned short (*As)[BM][BK] = (unsigned short(*)[BM][BK])smem;            // [2]
  unsigned short (*Bs)[BN][BK] = (unsigned short(*)[BN][BK])(smem + 16384);  // [2]

  const int xcd = wg & 7;
  const int idx = wg >> 3;
  const int n0 = (xcd * 4 + (idx & 3)) * BN;
  const int m0 = ((idx >> 2) & 7) * BM;
  const int kz = idx >> 5;
  const int kbase = kz * KC;
  const int lane = t & 63;
  const int wid = t >> 6;
  const int wm = (wid >> 1) * 32;
  const int wn = (wid & 1) * 32;

  f32x4 zero = {0.f, 0.f, 0.f, 0.f};
  f32x4 acc[2][2];
  acc[0][0] = zero; acc[0][1] = zero; acc[1][0] = zero; acc[1][1] = zero;

  // T2 both-sides swizzle: pre-swizzled global source + linear LDS dest +
  // swizzled ds_read.
  const int r0 = t >> 3;
  const int sc = ((t & 7) ^ (r0 & 7)) * 8;
  const unsigned short* gA = A + (size_t)(m0 + r0) * HIDDEN + kbase + sc;
  const unsigned short* gB = Bt + (size_t)(n0 + r0) * HIDDEN + kbase + sc;
  char* lA = (char*)smem + wid * 1024;
  char* lB = (char*)smem + 16384 + wid * 1024;

#define STAGE(buf, kt)                                          \
  do {                                                          \
    const int ko = (kt)*BK;                                     \
    gload_lds16(gA + ko, lA + (buf)*8192);                      \
    gload_lds16(gA + 32 * HIDDEN + ko, lA + (buf)*8192 + 4096); \
    gload_lds16(gB + ko, lB + (buf)*8192);                      \
    gload_lds16(gB + 32 * HIDDEN + ko, lB + (buf)*8192 + 4096); \
  } while (0)

  const int row_a0 = wm + (lane & 15);
  const int row_a1 = row_a0 + 16;
  const int row_b0 = wn + (lane & 15);
  const int row_b1 = row_b0 + 16;
  const int q = lane >> 4;  // 0..3

#define COMPUTE(buf)                                                                    \
  do {                                                                                  \
    _Pragma("unroll") for (int ks = 0; ks < 2; ++ks) {                                  \
      const int cnk = ks * 4 + q;                                                       \
      bf16x8 a0 = *(const bf16x8*)&As[buf][row_a0][(cnk ^ (row_a0 & 7)) * 8];           \
      bf16x8 a1 = *(const bf16x8*)&As[buf][row_a1][(cnk ^ (row_a1 & 7)) * 8];           \
      bf16x8 b0 = *(const bf16x8*)&Bs[buf][row_b0][(cnk ^ (row_b0 & 7)) * 8];           \
      bf16x8 b1 = *(const bf16x8*)&Bs[buf][row_b1][(cnk ^ (row_b1 & 7)) * 8];           \
      acc[0][0] = __builtin_amdgcn_mfma_f32_16x16x32_bf16(a0, b0, acc[0][0], 0, 0, 0);  \
      acc[0][1] = __builtin_amdgcn_mfma_f32_16x16x32_bf16(a0, b1, acc[0][1], 0, 0, 0);  \
      acc[1][0] = __builtin_amdgcn_mfma_f32_16x16x32_bf16(a1, b0, acc[1][0], 0, 0, 0);  \
      acc[1][1] = __builtin_amdgcn_mfma_f32_16x16x32_bf16(a1, b1, acc[1][1], 0, 0, 0);  \
    }                                                                                   \
  } while (0)

  // Counted-vmcnt pipeline, 2 buffers, depth-1 in flight (r12-validated).
  STAGE(0, 0);
  for (int kt = 0; kt < NT; ++kt) {
    const int buf = kt & 1;
    if (kt + 1 < NT) {
      STAGE(buf ^ 1, kt + 1);
      asm volatile("s_waitcnt vmcnt(4)" ::: "memory");
    } else {
      asm volatile("s_waitcnt vmcnt(0)" ::: "memory");
    }
    __builtin_amdgcn_s_barrier();  // stage kt visible to all waves
    COMPUTE(buf);
    asm volatile("s_waitcnt lgkmcnt(0)" ::: "memory");
    __builtin_amdgcn_s_barrier();  // all waves done reading buf -> safe to restage
  }

  unsigned short* p = part + (size_t)kz * ((size_t)BATCH * HIDDEN);
  const int rb = m0 + wm + (q << 2);
  const int cb = n0 + wn + (lane & 15);
#pragma unroll
  for (int fm = 0; fm < 2; ++fm)
#pragma unroll
    for (int fn = 0; fn < 2; ++fn)
#pragma unroll
      for (int j = 0; j < 4; ++j)
        p[(size_t)(rb + fm * 16 + j) * HIDDEN + cb + fn * 16] = f2bf(acc[fm][fn][j]);
}

// ---- per-layer epilogue: sum bf16 partials, gate, tanh; state bf16 in-place ----
__global__ __launch_bounds__(256) void k_reduce(const unsigned short* __restrict__ part,
                                                const float* __restrict__ prevf,
                                                unsigned short* __restrict__ stb,
                                                const float* __restrict__ ihl,
                                                const int* __restrict__ token,
                                                float* __restrict__ outf) {
  const int idx = (blockIdx.x * 256 + threadIdx.x) * 4;
  const int m = idx >> 11;
  const int n = idx & 2047;
  const size_t MN = (size_t)BATCH * HIDDEN;
  float s[4] = {0.f, 0.f, 0.f, 0.f};
#pragma unroll
  for (int kz = 0; kz < SPLITK; ++kz) {
    union { uint2 u; unsigned short h[4]; } v;
    v.u = *(const uint2*)(part + kz * MN + idx);
#pragma unroll
    for (int j = 0; j < 4; ++j) s[j] += bf2f(v.h[j]);
  }
  float pv[4];
  if (prevf) {
    float4 p4 = *(const float4*)(prevf + idx);
    pv[0] = p4.x; pv[1] = p4.y; pv[2] = p4.z; pv[3] = p4.w;
  } else {
    union { uint2 u; unsigned short h[4]; } p2;
    p2.u = *(const uint2*)(stb + idx);
#pragma unroll
    for (int j = 0; j < 4; ++j) pv[j] = bf2f(p2.h[j]);
  }
  const int tok = token[m];
  float4 g = *(const float4*)(ihl + (size_t)tok * HIDDEN + n);
  float r[4];
  r[0] = tanh_fast(pv[0] + s[0] * g.x);
  r[1] = tanh_fast(pv[1] + s[1] * g.y);
  r[2] = tanh_fast(pv[2] + s[2] * g.z);
  r[3] = tanh_fast(pv[3] + s[3] * g.w);
  if (outf) {
    float4 o4 = {r[0], r[1], r[2], r[3]};
    *(float4*)(outf + idx) = o4;
  } else {
    union { unsigned short h[4]; uint2 u; } o;
    o.h[0] = f2bf(r[0]); o.h[1] = f2bf(r[1]); o.h[2] = f2bf(r[2]); o.h[3] = f2bf(r[3]);
    *(uint2*)(stb + idx) = o.u;
  }
}

extern "C" void kernel_launch(void* const* d_in, const int* in_sizes, int n_in,
                              void* d_out, int out_size, void* d_ws, size_t ws_size,
                              hipStream_t stream) {
  const float* state = (const float*)d_in[0];
  const int* token = (const int*)d_in[1];
  const float* ih = (const float*)d_in[2];
  const float* hh = (const float*)d_in[3];
  float* out = (float*)d_out;

  // ws layout (16B-aligned):
  //   Bt   : 6*2048*2048 bf16 = 50331648 B
  //   stb  : 512*2048 bf16    =  2097152 B
  //   part : 4*512*2048 bf16  =  8388608 B
  char* ws = (char*)d_ws;
  unsigned short* bt = (unsigned short*)ws;
  size_t off = (size_t)NLAYERS * HIDDEN * HIDDEN * 2;
  unsigned short* stb = (unsigned short*)(ws + off);
  off += (size_t)BATCH * HIDDEN * 2;
  unsigned short* part = (unsigned short*)(ws + off);

  k_prep0<<<dim3(TRANS_BLOCKS + CVT_BLOCKS), 256, 0, stream>>>(hh, bt, state, stb);

  for (int l = 0; l < NLAYERS; ++l) {
    const bool last = (l == NLAYERS - 1);
    const int nblocks = GEMM_BLOCKS + (last ? 0 : TRANS_BLOCKS);
    k_gemm_trans<<<dim3(nblocks), 256, 0, stream>>>(
        stb, bt + (size_t)l * HIDDEN * HIDDEN, part,
        last ? nullptr : hh + (size_t)(l + 1) * HIDDEN * HIDDEN,
        last ? nullptr : bt + (size_t)(l + 1) * HIDDEN * HIDDEN);
    k_reduce<<<dim3((BATCH * HIDDEN) / 1024), 256, 0, stream>>>(
        part, l == 0 ? state : nullptr, stb,
        ih + (size_t)l * VOCAB * HIDDEN, token, last ? out : nullptr);
  }
}